// Round 1
// baseline (105.240 us; speedup 1.0000x reference)
//
#include <hip/hip_runtime.h>

// Problem constants (B=8, K=8192 from setup_inputs).
#define KPTS 8192
#define BATCH 8
#define NT 8                    // n-slices (per-block n range = 1024)
#define N_SLICE (KPTS / NT)
#define MT 8                    // m-tiles (per-block m range = 1024)
#define M_TILE (KPTS / MT)
#define TPB 256
#define ACC (M_TILE / TPB)      // 4 adv-point accumulators per thread

// ws[b*K+m] holds min_n ||ori_n - adv_m||^2 as nonneg-float bit pattern.
__global__ void init_ws(float* ws) {
    int i = blockIdx.x * blockDim.x + threadIdx.x;
    if (i < BATCH * KPTS) ws[i] = __builtin_huge_valf();
}

__global__ __launch_bounds__(TPB) void phaseA(const float* __restrict__ adv,
                                              const float* __restrict__ ori,
                                              unsigned int* __restrict__ ws) {
    __shared__ float4 sO[N_SLICE];   // (x, y, z, x^2+y^2+z^2) per ori point

    const int bid = blockIdx.x;              // grid = B * MT * NT = 512
    const int b  = bid >> 6;
    const int mt = (bid >> 3) & (MT - 1);
    const int nt = bid & (NT - 1);
    const int tid = threadIdx.x;

    // Stage this block's ori n-slice into LDS with precomputed ||o||^2.
    const float* op = ori + ((size_t)b * KPTS + (size_t)nt * N_SLICE) * 3;
    for (int p = tid; p < N_SLICE; p += TPB) {
        float x = op[3 * p + 0];
        float y = op[3 * p + 1];
        float z = op[3 * p + 2];
        sO[p] = make_float4(x, y, z, x * x + y * y + z * z);
    }

    // Per-thread adv points: fold -2 into coords; aa added after the min.
    float nax[ACC], nay[ACC], naz[ACC], aa[ACC], mn[ACC];
    const float* ap = adv + ((size_t)b * KPTS + (size_t)mt * M_TILE) * 3;
#pragma unroll
    for (int i = 0; i < ACC; ++i) {
        int m = tid + i * TPB;
        float x = ap[3 * m + 0];
        float y = ap[3 * m + 1];
        float z = ap[3 * m + 2];
        nax[i] = -2.0f * x;
        nay[i] = -2.0f * y;
        naz[i] = -2.0f * z;
        aa[i]  = x * x + y * y + z * z;
        mn[i]  = __builtin_huge_valf();
    }

    __syncthreads();

    // Inner loop: 4 VALU per pair (3 fma + 1 min); sO[n] is a wave-uniform
    // ds_read_b128 broadcast (conflict-free).
#pragma unroll 8
    for (int n = 0; n < N_SLICE; ++n) {
        float4 o = sO[n];
#pragma unroll
        for (int i = 0; i < ACC; ++i) {
            float t = fmaf(o.x, nax[i], o.w);
            t = fmaf(o.y, nay[i], t);
            t = fmaf(o.z, naz[i], t);
            mn[i] = fminf(mn[i], t);
        }
    }

    // Combine partial mins across n-slices: nonneg floats order like uints.
    unsigned int* wsb = ws + (size_t)b * KPTS + (size_t)mt * M_TILE;
#pragma unroll
    for (int i = 0; i < ACC; ++i) {
        float v = fmaxf(aa[i] + mn[i], 0.0f);
        atomicMin(wsb + tid + i * TPB, __float_as_uint(v));
    }
}

__global__ __launch_bounds__(TPB) void phaseB(const float* __restrict__ ws,
                                              const float* __restrict__ w,
                                              float* __restrict__ out) {
    const int b = blockIdx.x;
    const int tid = threadIdx.x;

    float mx = -1.0f;
    for (int m = tid; m < KPTS; m += TPB)
        mx = fmaxf(mx, ws[(size_t)b * KPTS + m]);

    // wave64 shuffle max-reduce, then cross-wave via LDS
#pragma unroll
    for (int off = 32; off; off >>= 1)
        mx = fmaxf(mx, __shfl_down(mx, off, 64));

    __shared__ float red[TPB / 64];
    if ((tid & 63) == 0) red[tid >> 6] = mx;
    __syncthreads();
    if (tid == 0) {
        float m2 = red[0];
#pragma unroll
        for (int i = 1; i < TPB / 64; ++i) m2 = fmaxf(m2, red[i]);
        atomicAdd(out, m2 * w[b] * (1.0f / BATCH));
    }
}

extern "C" void kernel_launch(void* const* d_in, const int* in_sizes, int n_in,
                              void* d_out, int out_size, void* d_ws, size_t ws_size,
                              hipStream_t stream) {
    const float* adv = (const float*)d_in[0];   // [B, K, 3]
    const float* ori = (const float*)d_in[1];   // [B, K, 3]
    const float* w   = (const float*)d_in[2];   // [B]
    float* out = (float*)d_out;                 // scalar
    float* ws  = (float*)d_ws;                  // B*K floats = 256 KB

    hipMemsetAsync(out, 0, sizeof(float), stream);
    init_ws<<<(BATCH * KPTS + TPB - 1) / TPB, TPB, 0, stream>>>(ws);
    phaseA<<<BATCH * MT * NT, TPB, 0, stream>>>(adv, ori, (unsigned int*)ws);
    phaseB<<<BATCH, TPB, 0, stream>>>(ws, w, out);
}